// Round 10
// baseline (70.217 us; speedup 1.0000x reference)
//
#include <hip/hip_runtime.h>
#include <hip/hip_bf16.h>

typedef __attribute__((ext_vector_type(8)))  short short8;
typedef __attribute__((ext_vector_type(4)))  float f32x4;
typedef __attribute__((ext_vector_type(16))) float f32x16;

#define CIN   16
#define COUT  64
#define HH    256
#define WW    256
#define OHH   254
#define OWW   254

// LDS patch (per buffer): [2 cihalf][34 h][36 w][8 ci] bf16, 16B cells.
// ci-half stride padded +16B so halves are bank-rotated. Per-buffer 19600
// ushorts = 39,200 B; two buffers = 78,400 B -> 2 blocks/CU.
#define HSTR   (36 * 8)              // 288 ushorts per h row
#define HALF   (34 * HSTR + 8)       // 9800 ushorts per ci-half
#define BUFU   (2 * HALF)            // ushorts per tile buffer

__device__ __forceinline__ ushort f2bf(float f) {
    unsigned u = __builtin_bit_cast(unsigned, f);
    unsigned r = (u + 0x7fffu + ((u >> 16) & 1u)) >> 16;
    return (ushort)r;
}

// fast tanh(tanh(x)): exp2-based (verified absmax 3.9e-3 in R1-R9)
__device__ __forceinline__ float dtanh2(float x) {
    const float K = 2.8853900817779268f;   // 2*log2(e)
    float xc = fminf(fmaxf(x, -9.0f), 9.0f);
    float e1 = __builtin_amdgcn_exp2f(K * xc);
    float t1 = 1.0f - 2.0f * __builtin_amdgcn_rcpf(e1 + 1.0f);
    float e2 = __builtin_amdgcn_exp2f(K * t1);
    return 1.0f - 2.0f * __builtin_amdgcn_rcpf(e2 + 1.0f);
}

// Weights fp32 OIHW [64][16][3][3] -> 32x32x16 A-fragments:
// wfrag[tap][j][lane][r]: channel row = j*32+(lane&31), ci = 8*(lane>>5)+r.
__global__ void prep_weights(const float* __restrict__ wsrc, ushort* __restrict__ wfrag) {
    int idx = blockIdx.x * 256 + threadIdx.x;
    if (idx >= 9216) return;
    int r    = idx & 7;
    int lane = (idx >> 3) & 63;
    int j    = (idx >> 9) & 1;
    int tap  = idx >> 10;                 // 0..8
    int ci   = 8 * (lane >> 5) + r;
    int co   = j * 32 + (lane & 31);
    int kh   = tap / 3, kw = tap - 3 * kh;
    wfrag[idx] = f2bf(wsrc[(co * CIN + ci) * 9 + kh * 3 + kw]);
}

// Working set ~236 VGPR (72 wf + 80 asm-held prefetch + 64 acc/bias + addr).
// (256,2) = 256-reg budget; do NOT cap below working set (R2/R6 spills).
__global__ __launch_bounds__(256, 2) void conv_min_tanh(
        const float* __restrict__ x, const ushort* __restrict__ wfrag,
        const float* __restrict__ bias, float* __restrict__ out) {
    __shared__ ushort lds[2 * BUFU];         // 78,400 B

    const int tid = threadIdx.x;
    const int oh0 = blockIdx.y * 32;
    const int ow0 = blockIdx.x * 32;
    const int n0  = blockIdx.z * 4;          // 4 images pipelined per block
    const int HW  = HH * WW;

    // ---- per-slot staging constants (identical across the 4 tiles) ----
    // slot = (hp 0..33, ciq 0..3, w4 0..8): float4 of 4 w for ci=4ciq..4ciq+3
    int goff[5], loff[5];
#pragma unroll
    for (int s = 0; s < 5; ++s) {
        int pos = tid + s * 256;
        if (pos > 1223) pos = 1223;          // dup-stage: same-value write, benign
        int hp  = pos / 36;
        int r2  = pos - hp * 36;
        int ciq = r2 / 9;
        int w4  = r2 - ciq * 9;
        int hg  = min(oh0 + hp, HH - 1);     // clamped edges; outputs masked at store
        int wg  = min(ow0 + 4 * w4, WW - 4); // keeps 16B alignment
        goff[s] = (ciq * 4) * HW + hg * WW + wg;
        loff[s] = (ciq >> 1) * HALF + (hp * 36 + 4 * w4) * 8 + (ciq & 1) * 4;
    }

    // prefetch registers, held in flight across compute by asm volatile issue
    f32x4 r[5][4];
    auto issue_loads = [&](const float* xb) {
#pragma unroll
        for (int s = 0; s < 5; ++s) {
            const float* p = xb + goff[s];
            asm volatile("global_load_dwordx4 %0, %1, off"
                         : "=v"(r[s][0]) : "v"(p) : "memory");
            asm volatile("global_load_dwordx4 %0, %1, off"
                         : "=v"(r[s][1]) : "v"(p + HW) : "memory");
            asm volatile("global_load_dwordx4 %0, %1, off"
                         : "=v"(r[s][2]) : "v"(p + 2 * HW) : "memory");
            asm volatile("global_load_dwordx4 %0, %1, off"
                         : "=v"(r[s][3]) : "v"(p + 3 * HW) : "memory");
        }
    };
    auto write_all = [&](int base) {
#pragma unroll
        for (int s = 0; s < 5; ++s) {
            ushort* dst = &lds[base + loff[s]];
#pragma unroll
            for (int e = 0; e < 4; ++e) {
                unsigned lo, hi;
                asm("v_cvt_pk_bf16_f32 %0, %1, %2" : "=v"(lo) : "v"(r[s][0][e]), "v"(r[s][1][e]));
                asm("v_cvt_pk_bf16_f32 %0, %1, %2" : "=v"(hi) : "v"(r[s][2][e]), "v"(r[s][3][e]));
                uint2 pk; pk.x = lo; pk.y = hi;
                *reinterpret_cast<uint2*>(dst + e * 8) = pk;
            }
        }
    };

    const int lane  = tid & 63;
    const int wid   = tid >> 6;          // wave: rows wid*8 .. wid*8+7
    const int px    = lane & 31;         // output pixel column
    const int khalf = lane >> 5;         // ci-half (k = 8*khalf + r)

    // ---- both weight tiles, 9 taps (A-operand) -> 72 VGPRs ----
    short8 wf[9][2];
#pragma unroll
    for (int tap = 0; tap < 9; ++tap) {
        wf[tap][0] = *reinterpret_cast<const short8*>(wfrag + ((tap * 2 + 0) * 64 + lane) * 8);
        wf[tap][1] = *reinterpret_cast<const short8*>(wfrag + ((tap * 2 + 1) * 64 + lane) * 8);
    }
    // bias -> acc init. D row (channel-in-tile) = (r&3) + 8*(r>>2) + 4*khalf.
    f32x16 bi0, bi1;
#pragma unroll
    for (int q = 0; q < 4; ++q) {
        f32x4 b0 = *reinterpret_cast<const f32x4*>(bias +  0 + 4 * khalf + 8 * q);
        f32x4 b1 = *reinterpret_cast<const f32x4*>(bias + 32 + 4 * khalf + 8 * q);
#pragma unroll
        for (int s = 0; s < 4; ++s) { bi0[q * 4 + s] = b0[s]; bi1[q * 4 + s] = b1[s]; }
    }

    // B-fragment LDS offsets (ushorts) per tap, within a buffer
    int boff[9];
#pragma unroll
    for (int tap = 0; tap < 9; ++tap) {
        int kh = tap / 3, kw = tap - 3 * kh;
        boff[tap] = khalf * HALF + (wid * 8 + kh) * HSTR + (px + kw) * 8;
    }

    auto compute = [&](int base, int n) {
#pragma unroll
        for (int i = 0; i < 8; ++i) {
            f32x16 a0 = bi0, a1 = bi1;
#pragma unroll
            for (int tap = 0; tap < 9; ++tap) {
                short8 b = *reinterpret_cast<const short8*>(&lds[base + boff[tap] + i * HSTR]);
                a0 = __builtin_amdgcn_mfma_f32_32x32x16_bf16(wf[tap][0], b, a0, 0, 0, 0);
                a1 = __builtin_amdgcn_mfma_f32_32x32x16_bf16(wf[tap][1], b, a1, 0, 0, 0);
            }
            // min over 32 in-lane channel rows, then xor32 across ci-halves
            float v = fminf(a0[0], a1[0]);
#pragma unroll
            for (int q = 1; q < 16; ++q) v = fminf(v, fminf(a0[q], a1[q]));
            v = fminf(v, __shfl_xor(v, 32, 64));
            const float y  = dtanh2(v);
            const int   oh = oh0 + wid * 8 + i;
            const int   ow = ow0 + px;
            if (lane < 32 && oh < OHH && ow < OWW)
                out[((size_t)n * OHH + oh) * OWW + ow] = y;
        }
    };

    // ---- pipelined 4-tile loop: issue(t+1) -> compute(t) -> wait+write(t+1) ----
    issue_loads(x + (size_t)n0 * CIN * HW);
    asm volatile("s_waitcnt vmcnt(0)" ::: "memory");
    write_all(0);
    __syncthreads();
    int cur = 0;
#pragma unroll
    for (int t = 0; t < 4; ++t) {
        if (t < 3)
            issue_loads(x + (size_t)(n0 + t + 1) * CIN * HW);  // in flight during compute
        compute(cur * BUFU, n0 + t);
        if (t < 3) {
            asm volatile("s_waitcnt vmcnt(0)" ::: "memory");
            write_all((cur ^ 1) * BUFU);
        }
        __syncthreads();
        cur ^= 1;
    }
}

extern "C" void kernel_launch(void* const* d_in, const int* in_sizes, int n_in,
                              void* d_out, int out_size, void* d_ws, size_t ws_size,
                              hipStream_t stream) {
    const float* x = (const float*)d_in[0];
    const float* w = (const float*)d_in[1];
    const float* b = (const float*)d_in[2];
    float* out     = (float*)d_out;
    ushort* wfrag  = (ushort*)d_ws;          // 18 KiB

    prep_weights<<<36, 256, 0, stream>>>(w, wfrag);
    dim3 grid(8, 8, 8);                      // (owT, ohT, n/4): 512 blocks, 2/CU, 4-tile pipeline
    conv_min_tanh<<<grid, dim3(256, 1, 1), 0, stream>>>(x, wfrag, b, out);
}